// Round 1
// 456.379 us; speedup vs baseline: 1.0974x; 1.0974x over previous
//
#include <hip/hip_runtime.h>

typedef unsigned short u16;
typedef unsigned int   u32;

#define NB   32
#define CIN  512
#define CM   128
#define P2   256
#define HW   3136
#define HD   56

typedef __attribute__((ext_vector_type(8))) short           short8;
typedef __attribute__((ext_vector_type(8))) unsigned short  ushort8;
typedef __attribute__((ext_vector_type(4))) unsigned short  ushort4_t;
typedef __attribute__((ext_vector_type(4))) float           f32x4;

__device__ __forceinline__ float b2f(u16 u) {
    union { u32 i; float f; } v; v.i = ((u32)u) << 16; return v.f;
}
__device__ __forceinline__ u16 f2b(float f) {
    u32 u = __builtin_bit_cast(u32, f);
    u32 r = (u + 0x7fffu + ((u >> 16) & 1u)) >> 16;
    return (u16)r;
}

// ---------------- kernel 0: zero xm + convert weights f32 -> bf16 ----------------
__global__ __launch_bounds__(256) void init_kernel(const float* __restrict__ Wc,
                                                   const float* __restrict__ Wf,
                                                   u16* __restrict__ Wcb,
                                                   u16* __restrict__ Wfb,
                                                   float* __restrict__ xm) {
    int i = blockIdx.x * 256 + threadIdx.x;
    if (i < CM * CIN) { Wcb[i] = f2b(Wc[i]); return; }
    i -= CM * CIN;
    if (i < P2 * CM) { Wfb[i] = f2b(Wf[i]); return; }
    i -= P2 * CM;
    if (i < NB * CIN) xm[i] = 0.f;
}

// ---------------- kernel 2: g[n,cm] = relu(W_conv . mean + b) ----------------
__global__ __launch_bounds__(128) void g_kernel(const float* __restrict__ Wc,
                                                const float* __restrict__ bc,
                                                const float* __restrict__ xm,
                                                float* __restrict__ g) {
    const int n = blockIdx.x, cm = threadIdx.x;
    __shared__ float xs[CIN];
    for (int i = threadIdx.x; i < CIN; i += 128)
        xs[i] = xm[n * CIN + i] * (1.0f / HW);
    __syncthreads();
    const float* wrow = Wc + (size_t)cm * CIN;
    float acc = 0.f;
    for (int c = 0; c < CIN; ++c) acc += wrow[c] * xs[c];
    acc += bc[cm];
    g[n * CM + cm] = fmaxf(acc, 0.f);
}

// ---------------- kernel 1: f = relu(Wconv @ x), also accumulate mean ----------------
// Out[(n*ch_stride + m)*HW + hw] = relu(sum_k W[m][k]*In[n][k][hw] + bias[m])
// block 256 thr (4 waves), tile 128(m) x 128(hw), K-step 32, mfma 16x16x32 bf16.
// Input f32 converted on the fly (+0x8000 round + v_perm pack); sum_hw accumulated
// into xm via 16-lane shfl reduce + atomicAdd.
__global__ __launch_bounds__(256) void gemm1_kernel(
    const float* __restrict__ In,
    const u16* __restrict__ Wm, const float* __restrict__ bias,
    u16* __restrict__ Out, float* __restrict__ xm)
{
    __shared__ u16 ldsT[128 * 36];   // [hw_col][k] transposed, stride 36 (pad 4)

    const int n    = blockIdx.z;
    const int hw0  = blockIdx.x * 128;
    const int mblk = blockIdx.y * 128;
    const int tid  = threadIdx.x;
    const int wave = tid >> 6, lane = tid & 63;
    const int wm   = (wave >> 1) * 64;   // wave m-offset
    const int wn   = (wave & 1) * 64;    // wave hw-offset
    const int qa   = lane >> 4;          // k-quad 0..3
    const int l15  = lane & 15;

    f32x4 acc[4][4] = {};

    // staging assignment: thread -> 2 k-rows x 8 hw-cols
    const int kpair = tid >> 4;            // 0..15 -> k rows 2*kpair, 2*kpair+1
    const int c0    = (tid & 15) * 8;      // hw col group
    const int hwc   = hw0 + c0;
    const bool cok  = (hwc < HW);

    for (int k0 = 0; k0 < CIN; k0 += 32) {
        __syncthreads();
        u32 pk[8];
        {
            f32x4 a0 = {0,0,0,0}, a1 = {0,0,0,0}, d0 = {0,0,0,0}, d1 = {0,0,0,0};
            if (cok) {
                const float* p0 = In + (size_t)n * CIN * HW
                                + (size_t)(k0 + kpair * 2) * HW + hwc;
                a0 = *(const f32x4*)p0;
                a1 = *(const f32x4*)(p0 + 4);
                d0 = *(const f32x4*)(p0 + HW);
                d1 = *(const f32x4*)(p0 + HW + 4);
            }
            float fa[8] = {a0[0],a0[1],a0[2],a0[3],a1[0],a1[1],a1[2],a1[3]};
            float fb[8] = {d0[0],d0[1],d0[2],d0[3],d1[0],d1[1],d1[2],d1[3]};
            #pragma unroll
            for (int e = 0; e < 8; ++e) {
                u32 ua = __builtin_bit_cast(u32, fa[e]) + 0x8000u;
                u32 ub = __builtin_bit_cast(u32, fb[e]) + 0x8000u;
                pk[e] = __builtin_amdgcn_perm(ub, ua, 0x07060302u);  // (hi16(ub)<<16)|hi16(ua)
            }
            float s0 = fa[0]+fa[1]+fa[2]+fa[3]+fa[4]+fa[5]+fa[6]+fa[7];
            float s1 = fb[0]+fb[1]+fb[2]+fb[3]+fb[4]+fb[5]+fb[6]+fb[7];
            #pragma unroll
            for (int off = 8; off > 0; off >>= 1) {
                s0 += __shfl_xor(s0, off, 16);
                s1 += __shfl_xor(s1, off, 16);
            }
            if ((tid & 15) == 0) {
                atomicAdd(&xm[n * CIN + k0 + kpair * 2],     s0);
                atomicAdd(&xm[n * CIN + k0 + kpair * 2 + 1], s1);
            }
        }
        #pragma unroll
        for (int e = 0; e < 8; ++e)
            *(u32*)&ldsT[(c0 + e) * 36 + kpair * 2] = pk[e];
        __syncthreads();

        short8 a[4];
        #pragma unroll
        for (int mt = 0; mt < 4; ++mt) {
            int row = mblk + wm + mt * 16 + l15;
            a[mt] = *(const short8*)(Wm + (size_t)row * CIN + k0 + qa * 8);
        }
        #pragma unroll
        for (int nt = 0; nt < 4; ++nt) {
            int c = wn + nt * 16 + l15;
            union { ushort4_t h[2]; short8 v; } bu;
            bu.h[0] = *(const ushort4_t*)&ldsT[c * 36 + qa * 8];
            bu.h[1] = *(const ushort4_t*)&ldsT[c * 36 + qa * 8 + 4];
            short8 b = bu.v;
            #pragma unroll
            for (int mt = 0; mt < 4; ++mt)
                acc[mt][nt] = __builtin_amdgcn_mfma_f32_16x16x32_bf16(a[mt], b, acc[mt][nt], 0, 0, 0);
        }
    }

    // epilogue: C/D layout col=lane&15, row=(lane>>4)*4+reg
    const int r4 = qa * 4;
    #pragma unroll
    for (int nt = 0; nt < 4; ++nt) {
        int colhw = hw0 + wn + nt * 16 + l15;
        if (colhw >= HW) continue;
        #pragma unroll
        for (int mt = 0; mt < 4; ++mt) {
            int mbase = mblk + wm + mt * 16 + r4;
            #pragma unroll
            for (int r = 0; r < 4; ++r) {
                int m = mbase + r;
                float v = fmaxf(acc[mt][nt][r] + bias[m], 0.f);
                Out[((size_t)n * CM + m) * HW + colhw] = f2b(v);
            }
        }
    }
}

// ---------------- kernel 4: both depthwise branches ----------------
// Zero-padded [60][60] f32 plane in LDS (no bounds checks); each thread computes
// 8 contiguous px with a 12-float register row window reused across all taps of
// both branches (5x5 dil1 and 3x3 dil2 share rows -2/0/+2).
#define PD 60
__global__ __launch_bounds__(256) void dw_kernel(
    const u16* __restrict__ f, const float* __restrict__ g,
    const float* __restrict__ wk,  const float* __restrict__ bk,
    const float* __restrict__ wck, const float* __restrict__ bck,
    const float* __restrict__ wk2, const float* __restrict__ bk2,
    const float* __restrict__ wck2,const float* __restrict__ bck2,
    u16* __restrict__ o1, u16* __restrict__ o2)
{
    const int ncm = blockIdx.x;
    __shared__ float fpl[PD * PD];          // 14.4 KB, +-2 halo, zero-padded
    __shared__ float kc1[25], kc2[9];

    // phase A: zero whole plane + compute dynamic kernel coefficients
    {
        f32x4 z = {0.f, 0.f, 0.f, 0.f};
        f32x4* fv = (f32x4*)fpl;
        for (int i = threadIdx.x; i < PD * PD / 4; i += 256) fv[i] = z;
    }
    const float gv = g[ncm];
    if (threadIdx.x < 25) {
        int t = threadIdx.x;
        kc1[t] = (gv * wk[t] + bk[t]) * wck[0] + bck[0];
    } else if (threadIdx.x >= 32 && threadIdx.x < 41) {
        int t = threadIdx.x - 32;
        kc2[t] = (gv * wk2[t] + bk2[t]) * wck2[0] + bck2[0];
    }
    __syncthreads();

    // phase B: fill interior (bf16 -> f32)
    const size_t base = (size_t)ncm * HW;
    const u32* fp = (const u32*)(f + base);
    for (int i = threadIdx.x; i < HW / 2; i += 256) {
        u32 v = fp[i];
        int px = 2 * i;
        int h = px / HD, w = px - h * HD;   // w even
        float* dst = &fpl[(h + 2) * PD + (w + 2)];
        dst[0] = b2f((u16)v);
        dst[1] = b2f((u16)(v >> 16));
    }
    __syncthreads();

    // phase C: compute. unit = 8 contiguous px; 7 groups x 56 rows = 392 units
    u32* o1p = (u32*)(o1 + base);
    u32* o2p = (u32*)(o2 + base);
    for (int u = threadIdx.x; u < 392; u += 256) {
        int h  = u / 7;
        int gq = u - h * 7;
        int w0 = gq * 8;
        float a1[8] = {}, a2[8] = {};
        #pragma unroll
        for (int di = 0; di < 5; ++di) {
            const float* row = &fpl[(h + di) * PD + w0];
            float r[12];
            #pragma unroll
            for (int x = 0; x < 12; ++x) r[x] = row[x];
            #pragma unroll
            for (int j = 0; j < 5; ++j) {
                float kv = kc1[di * 5 + j];
                #pragma unroll
                for (int e = 0; e < 8; ++e) a1[e] = fmaf(kv, r[j + e], a1[e]);
            }
            if ((di & 1) == 0) {
                int i2 = di >> 1;
                #pragma unroll
                for (int j = 0; j < 3; ++j) {
                    float kv = kc2[i2 * 3 + j];
                    #pragma unroll
                    for (int e = 0; e < 8; ++e) a2[e] = fmaf(kv, r[2 * j + e], a2[e]);
                }
            }
        }
        int ob = (h * HD + w0) >> 1;
        #pragma unroll
        for (int e = 0; e < 4; ++e) {
            o1p[ob + e] = (u32)f2b(a1[2 * e]) | ((u32)f2b(a1[2 * e + 1]) << 16);
            o2p[ob + e] = (u32)f2b(a2[2 * e]) | ((u32)f2b(a2[2 * e + 1]) << 16);
        }
    }
}

// ---------------- kernel 5: fuse GEMM, 256m x 64hw per block, K=128 staged once ----------------
// HW = 3136 = 49*64 exactly -> no hw bounds checks; o tile read exactly once.
#define FSTR 140   // u16 stride per col: 140 u16 = 35 dwords -> conflict-light b64 reads
__global__ __launch_bounds__(256) void fuse_kernel(
    const u16* __restrict__ o1, const u16* __restrict__ o2,
    const u16* __restrict__ Wfb, const float* __restrict__ bias,
    float* __restrict__ out)
{
    __shared__ u16 ldsT[64 * FSTR];   // [col 64][k 128], transposed

    const int n   = blockIdx.z;
    const int br  = blockIdx.y;
    const u16* In = br ? o2 : o1;
    const int ch_off = br ? P2 : 0;
    const int hw0 = blockIdx.x * 64;
    const int tid = threadIdx.x;
    const int wave = tid >> 6, lane = tid & 63;
    const int wm  = wave * 64;           // wave m-offset (4 waves cover m 0..255)
    const int qa  = lane >> 4, l15 = lane & 15;

    // stage o tile: [64 cols][128 k]; thread -> 2 k-rows x 8 cols, 2 phases
    {
        const int c0 = (tid & 7) * 8;
        const int kp = tid >> 3;         // 0..31
        #pragma unroll
        for (int kk = 0; kk < CM; kk += 64) {
            const u16* p0 = In + (size_t)n * CM * HW + (size_t)(kk + 2 * kp) * HW + hw0 + c0;
            ushort8 v0 = *(const ushort8*)p0;
            ushort8 v1 = *(const ushort8*)(p0 + HW);
            #pragma unroll
            for (int e = 0; e < 8; ++e)
                *(u32*)&ldsT[(c0 + e) * FSTR + kk + 2 * kp] = (u32)v0[e] | ((u32)v1[e] << 16);
        }
    }
    __syncthreads();

    f32x4 acc[4][4] = {};
    #pragma unroll
    for (int q = 0; q < 4; ++q) {        // K chunks of 32
        short8 a[4];
        #pragma unroll
        for (int mt = 0; mt < 4; ++mt) {
            int row = wm + mt * 16 + l15;
            a[mt] = *(const short8*)(Wfb + (size_t)row * CM + q * 32 + qa * 8);
        }
        #pragma unroll
        for (int nt = 0; nt < 4; ++nt) {
            int c = nt * 16 + l15;
            union { ushort4_t h[2]; short8 v; } bu;
            bu.h[0] = *(const ushort4_t*)&ldsT[c * FSTR + q * 32 + qa * 8];
            bu.h[1] = *(const ushort4_t*)&ldsT[c * FSTR + q * 32 + qa * 8 + 4];
            #pragma unroll
            for (int mt = 0; mt < 4; ++mt)
                acc[mt][nt] = __builtin_amdgcn_mfma_f32_16x16x32_bf16(a[mt], bu.v, acc[mt][nt], 0, 0, 0);
        }
    }

    const int r4 = qa * 4;
    #pragma unroll
    for (int nt = 0; nt < 4; ++nt) {
        int colhw = hw0 + nt * 16 + l15;
        #pragma unroll
        for (int mt = 0; mt < 4; ++mt) {
            int mbase = wm + mt * 16 + r4;
            #pragma unroll
            for (int r = 0; r < 4; ++r) {
                int m = mbase + r;
                float v = acc[mt][nt][r] + bias[m];
                out[((size_t)n * 512 + ch_off + m) * HW + colhw] = v;
            }
        }
    }
}

extern "C" void kernel_launch(void* const* d_in, const int* in_sizes, int n_in,
                              void* d_out, int out_size, void* d_ws, size_t ws_size,
                              hipStream_t stream) {
    const float* x     = (const float*)d_in[0];
    const float* Wconv = (const float*)d_in[1];
    const float* bconv = (const float*)d_in[2];
    const float* wk    = (const float*)d_in[3];
    const float* bk    = (const float*)d_in[4];
    const float* wck   = (const float*)d_in[5];
    const float* bck   = (const float*)d_in[6];
    const float* wk2   = (const float*)d_in[7];
    const float* bk2   = (const float*)d_in[8];
    const float* wck2  = (const float*)d_in[9];
    const float* bck2  = (const float*)d_in[10];
    const float* Wfuse = (const float*)d_in[11];
    const float* bfuse = (const float*)d_in[12];
    float* out = (float*)d_out;

    // workspace layout (all regions fully rewritten every call)
    float* xm  = (float*)d_ws;                // NB*CIN f32 (zeroed by init)
    float* g   = xm + NB * CIN;               // NB*CM f32
    u16*   Wcb = (u16*)(g + NB * CM);         // CM*CIN bf16
    u16*   Wfb = Wcb + CM * CIN;              // P2*CM bf16
    u16*   f   = Wfb + P2 * CM;               // NB*CM*HW bf16
    u16*   o1  = f  + (size_t)NB * CM * HW;   // NB*CM*HW bf16
    u16*   o2  = o1 + (size_t)NB * CM * HW;   // NB*CM*HW bf16

    {
        int tot = CM * CIN + P2 * CM + NB * CIN;
        init_kernel<<<dim3((tot + 255) / 256), 256, 0, stream>>>(Wconv, Wfuse, Wcb, Wfb, xm);
    }
    // f = relu(W_conv @ x) : M=128, K=512 ; also accumulates sum_hw(x) into xm
    gemm1_kernel<<<dim3(25, 1, NB), 256, 0, stream>>>(x, Wcb, bconv, f, xm);
    g_kernel<<<dim3(NB), 128, 0, stream>>>(Wconv, bconv, xm, g);
    dw_kernel<<<dim3(NB * CM), 256, 0, stream>>>(f, g, wk, bk, wck, bck,
                                                 wk2, bk2, wck2, bck2, o1, o2);
    // y1/y2 = W_fuse @ o1/o2 + b_fuse : M=256 per branch, K=128, hw tile 64
    fuse_kernel<<<dim3(49, 2, NB), 256, 0, stream>>>(o1, o2, Wfb, bfuse, out);
}